// Round 12
// baseline (2678.579 us; speedup 1.0000x reference)
//
#include <hip/hip_runtime.h>

#define DEVI __device__ __forceinline__

typedef __attribute__((ext_vector_type(8))) _Float16 halfx8;
typedef __attribute__((ext_vector_type(4))) short halfx4s;
typedef __attribute__((ext_vector_type(4))) float floatx4;

DEVI short f2h(float f) {
  _Float16 h = (_Float16)f;  // v_cvt_f16_f32, RNE
  return __builtin_bit_cast(short, h);
}

DEVI void gl_lds16(const void* g, void* l) {
  __builtin_amdgcn_global_load_lds(
      (const __attribute__((address_space(1))) void*)g,
      (__attribute__((address_space(3))) void*)l, 16, 0, 0);
}

// ---------------------------------------------------------------------------
// Generic NT GEMM (legacy 128x128 2-barrier structure) — kept for the small
// GEMMs G5/G6 (M or N == 512).
// ---------------------------------------------------------------------------
template <typename OutT, int BIAS>
__global__ __launch_bounds__(256) void gemm_nt(
    const short* __restrict__ A, const short* __restrict__ B,
    OutT* __restrict__ C, const float* __restrict__ bias,
    int K, int lda, int ldb, int ldc, float scale,
    long long a_s0, long long a_s1, long long b_s0, long long b_s1,
    long long c_s0, long long c_s1, int zdiv) {
  const int z = blockIdx.z;
  const int zb = z / zdiv, zh = z % zdiv;
  A += zb * a_s0 + zh * a_s1;
  B += zb * b_s0 + zh * b_s1;
  C += zb * c_s0 + zh * c_s1;

  const int m0 = blockIdx.y * 128, n0 = blockIdx.x * 128;
  const int t = threadIdx.x;
  const int wave = t >> 6, lane = t & 63;
  const int wm = wave >> 1, wn = wave & 1;

  __shared__ short As[128 * 32];
  __shared__ short Bs[128 * 32];

  floatx4 acc[4][4] = {};

  const char* ag = (const char*)(A + (long long)(m0 + (t >> 2)) * lda + (t & 3) * 8);
  const char* bg = (const char*)(B + (long long)(n0 + (t >> 2)) * ldb + (t & 3) * 8);
  const long long astep = (long long)lda * 2 * 64;
  const long long bstep = (long long)ldb * 2 * 64;
  short* asl = As + t * 8;
  short* bsl = Bs + t * 8;

  const int a_off = (wm * 64 + (lane & 15)) * 32 + (lane >> 4) * 8;
  const int b_off = (wn * 64 + (lane & 15)) * 32 + (lane >> 4) * 8;

  for (int kt = 0; kt < K; kt += 32) {
    __syncthreads();
    gl_lds16(ag, asl);
    gl_lds16(ag + astep, asl + 2048);
    gl_lds16(bg, bsl);
    gl_lds16(bg + bstep, bsl + 2048);
    ag += 64;
    bg += 64;
    __syncthreads();
    halfx8 af[4], bfr[4];
#pragma unroll
    for (int i = 0; i < 4; i++) af[i] = *(const halfx8*)(As + a_off + i * 16 * 32);
#pragma unroll
    for (int j = 0; j < 4; j++) bfr[j] = *(const halfx8*)(Bs + b_off + j * 16 * 32);
#pragma unroll
    for (int i = 0; i < 4; i++)
#pragma unroll
      for (int j = 0; j < 4; j++)
        acc[i][j] =
            __builtin_amdgcn_mfma_f32_16x16x32_f16(af[i], bfr[j], acc[i][j], 0, 0, 0);
  }

  const int lr = lane >> 4, lc = lane & 15;
#pragma unroll
  for (int i = 0; i < 4; i++) {
#pragma unroll
    for (int r = 0; r < 4; r++) {
      const int row = m0 + wm * 64 + i * 16 + lr * 4 + r;
      float bM = 0.f;
      if (BIAS == 1) bM = bias[row];
      const long long ro = (long long)row * ldc;
#pragma unroll
      for (int j = 0; j < 4; j++) {
        const int col = n0 + wn * 64 + j * 16 + lc;
        float v = acc[i][j][r] * scale;
        if (BIAS == 1) v += bM;
        if (BIAS == 2) v += bias[col];
        if constexpr (sizeof(OutT) == 2)
          C[ro + col] = f2h(v);
        else
          C[ro + col] = v;
      }
    }
  }
}

// ---------------------------------------------------------------------------
// 256x256 8-phase NT GEMM (T2+T3+T4+T5, m201-style). 512 thr = 8 waves
// (2M x 4N); wave owns 128x64; BK=64; nk = K/64 (even). LDS 128 KiB.
//
// Bank-conflict fix v3 (v1/v2 post-mortem): read byte = row*128 + chunk*16
// (chunk 0..7 within the 128B row). The row term contributes ZERO bank
// spread; within any 8 consecutive lanes (row = lane&15) all lanes share
// lane>>4, so a 1-bit XOR (v1: chunk-bit1, v2: chunk-bit2) leaves 4 lanes
// per 16B slot — explaining v1 and v2's bit-identical 7.55e7 conflicts.
// v3 uses the full 3-bit involution: stored_chunk = logical_chunk ^ (row&7).
// Every 8 consecutive lanes then cover all 8 slots exactly once ->
// conflict-free ds_read_b128 under any HW lane grouping.
// Rule #21 both-sides: write side (linear LDS dest, chunk t -> row t>>3,
// stored chunk t&7) inverse-swizzles the GLOBAL source column:
//   kbt = ((t&7) ^ ((t>>3)&7)) << 4.
// Read side: logical chunk = ks*4 + (lane>>4), row&7 = lane&7 (rb*16/cb*16/
// 64-row offsets all preserve row&7):
//   chunk' = ((ks ^ lane_b2) << 2) | ((lane>>4) ^ (lane&3))
// -> laneR gains ^(lane&3) in the h-field; xm = (lane&4)<<3 as before.
//
// vmcnt(6) ledger: PH3 entry has 14 outstanding ({B0,B1,A0}(j+1) staged in
// block j-1, A1(j+1)@PH0, {B0,B1,A0}(j+2)@PH1-3); vmcnt(6) drains exactly
// K-step j+1 before the seam barrier. Tail: vmcnt(0) when the issue stream
// thins. Every LDS slot overwrite issues after the phase whose lgkmcnt(0)
// + barrier drained that slot's last read (checked all 8 slots incl. seam).
// ---------------------------------------------------------------------------

#define LOAD_B(P)                                                            \
  _Pragma("unroll") for (int cb = 0; cb < 4; ++cb)                           \
      _Pragma("unroll") for (int ks = 0; ks < 2; ++ks)                       \
          bF[cb][ks] =                                                       \
              *(const halfx8*)(Br + (P)*16384 + cb * 1024 + ((ks * 32) ^ xm));

#define LOAD_A(P, DST, RBASE)                                                \
  _Pragma("unroll") for (int rb = 0; rb < 4; ++rb)                           \
      _Pragma("unroll") for (int ks = 0; ks < 2; ++ks)                       \
          DST[rb][ks] = *(const halfx8*)(Ar + (P)*16384 +                    \
                                         ((RBASE) + rb) * 1024 +             \
                                         ((ks * 32) ^ xm));

#define MFMA_Q(AF, RB0, CB0)                                                 \
  _Pragma("unroll") for (int rb = 0; rb < 4; ++rb)                           \
      _Pragma("unroll") for (int cb = 0; cb < 2; ++cb)                       \
          _Pragma("unroll") for (int ks = 0; ks < 2; ++ks)                   \
              acc[(RB0) + rb][(CB0) + cb] =                                  \
                  __builtin_amdgcn_mfma_f32_16x16x32_f16(                    \
                      AF[rb][ks], bF[(CB0) + cb][ks],                        \
                      acc[(RB0) + rb][(CB0) + cb], 0, 0, 0);

#define STAGE_A(PP, HH, JS)                                                  \
  {                                                                          \
    const char* s_ = Ag + (size_t)(HH) * (ldab << 7) + ((size_t)(JS) << 7);  \
    gl_lds16(s_, AsD + (PP)*16384 + (HH)*8192);                              \
    gl_lds16(s_ + (ldab << 6), AsD + (PP)*16384 + (HH)*8192 + 4096);         \
  }

#define STAGE_B(PP, HH, JS)                                                  \
  {                                                                          \
    const char* s_ = Bg + (size_t)(HH) * (ldbb << 7) + ((size_t)(JS) << 7);  \
    gl_lds16(s_, BsD + (PP)*16384 + (HH)*8192);                              \
    gl_lds16(s_ + (ldbb << 6), BsD + (PP)*16384 + (HH)*8192 + 4096);         \
  }

#define BLOCK256(P, J)                                                       \
  {                                                                          \
    halfx8 bF[4][2], aLo[4][2], aHi[4][2];                                   \
    /* PH0 */                                                                \
    LOAD_B(P);                                                               \
    LOAD_A(P, aLo, 0);                                                       \
    if ((J) + 1 < nk) STAGE_A((P) ^ 1, 1, (J) + 1);                          \
    __builtin_amdgcn_s_barrier();                                            \
    asm volatile("s_waitcnt lgkmcnt(0)" ::: "memory");                       \
    __builtin_amdgcn_s_setprio(1);                                           \
    MFMA_Q(aLo, 0, 0);                                                       \
    __builtin_amdgcn_s_setprio(0);                                           \
    __builtin_amdgcn_s_barrier();                                            \
    /* PH1 */                                                                \
    if ((J) + 2 < nk) STAGE_B(P, 0, (J) + 2);                                \
    __builtin_amdgcn_s_barrier();                                            \
    asm volatile("s_waitcnt lgkmcnt(0)" ::: "memory");                       \
    __builtin_amdgcn_s_setprio(1);                                           \
    MFMA_Q(aLo, 0, 2);                                                       \
    __builtin_amdgcn_s_setprio(0);                                           \
    __builtin_amdgcn_s_barrier();                                            \
    /* PH2 */                                                                \
    LOAD_A(P, aHi, 4);                                                       \
    if ((J) + 2 < nk) STAGE_B(P, 1, (J) + 2);                                \
    __builtin_amdgcn_s_barrier();                                            \
    asm volatile("s_waitcnt lgkmcnt(0)" ::: "memory");                       \
    __builtin_amdgcn_s_setprio(1);                                           \
    MFMA_Q(aHi, 4, 0);                                                       \
    __builtin_amdgcn_s_setprio(0);                                           \
    __builtin_amdgcn_s_barrier();                                            \
    /* PH3 */                                                                \
    if ((J) + 2 < nk) STAGE_A(P, 0, (J) + 2);                                \
    __builtin_amdgcn_s_barrier();                                            \
    asm volatile("s_waitcnt lgkmcnt(0)" ::: "memory");                       \
    __builtin_amdgcn_s_setprio(1);                                           \
    MFMA_Q(aHi, 4, 2);                                                       \
    __builtin_amdgcn_s_setprio(0);                                           \
    if ((J) + 2 < nk) {                                                      \
      asm volatile("s_waitcnt vmcnt(6)" ::: "memory");                       \
    } else {                                                                 \
      asm volatile("s_waitcnt vmcnt(0)" ::: "memory");                       \
    }                                                                        \
    __builtin_amdgcn_s_barrier();                                            \
  }

template <typename OutT, int BIAS>
__global__ __launch_bounds__(512, 2) void gemm256_nt(
    const short* __restrict__ A, const short* __restrict__ B,
    OutT* __restrict__ C, const float* __restrict__ bias,
    int K, int lda, int ldb, int ldc, float scale,
    long long a_s0, long long a_s1, long long b_s0, long long b_s1,
    long long c_s0, long long c_s1, int zdiv) {
  const int z = blockIdx.z;
  const int zb = z / zdiv, zh = z % zdiv;
  A += zb * a_s0 + zh * a_s1;
  B += zb * b_s0 + zh * b_s1;
  C += zb * c_s0 + zh * c_s1;

  const int m0 = blockIdx.y * 256, n0 = blockIdx.x * 256;
  const int t = threadIdx.x;
  const int wave = t >> 6, lane = t & 63;
  const int wm = wave >> 2, wn = wave & 3;  // 2 x 4 wave grid

  __shared__ short As[2][2][8192];  // [dbuf][half(128 rows)][128*64]
  __shared__ short Bs[2][2][8192];

  floatx4 acc[8][4] = {};

  // --- staging: chunk t covers row t>>3, stored chunk t&7; logical chunk
  //     = (t&7) ^ ((t>>3)&7)  (inverse of stored = logical ^ (row&7)) ---
  const size_t ldab = (size_t)lda * 2, ldbb = (size_t)ldb * 2;
  const int rowt = t >> 3;
  const int kbt = (((t & 7) ^ ((t >> 3) & 7)) << 4);  // inverse swizzle, bytes
  const char* Ag = (const char*)A + (size_t)(m0 + rowt) * ldab + kbt;
  const char* Bg = (const char*)B + (size_t)(n0 + rowt) * ldbb + kbt;
  short* AsD = &As[0][0][0] + t * 8;
  short* BsD = &Bs[0][0][0] + t * 8;

  // --- read addresses (shorts): row*64 + stored_chunk*8 with
  //     stored_chunk = ((ks ^ lane_b2)<<2) | ((lane>>4) ^ (lane&3));
  //     ks term applied in LOAD macros as (ks*32) ^ xm ---
  const int laneR = ((lane & 15) << 6) | ((((lane >> 4) ^ (lane & 3))) << 3);
  const int xm = (lane & 4) << 3;
  const short* Ar = &As[0][0][0] + wm * 8192 + laneR;
  const short* Br = &Bs[0][0][0] + (wn >> 1) * 8192 + (wn & 1) * 4096 + laneR;

  const int nk = K >> 6;

  // prologue: stage K-step 0 fully, then B0,B1,A0 of K-step 1
  STAGE_B(0, 0, 0);
  STAGE_B(0, 1, 0);
  STAGE_A(0, 0, 0);
  STAGE_A(0, 1, 0);
  STAGE_B(1, 0, 1);
  STAGE_B(1, 1, 1);
  STAGE_A(1, 0, 1);
  asm volatile("s_waitcnt vmcnt(6)" ::: "memory");
  __builtin_amdgcn_s_barrier();

  for (int j = 0; j < nk; j += 2) {
    BLOCK256(0, j)
    BLOCK256(1, j + 1)
  }

  // epilogue: C/D layout col = lane&15, row = (lane>>4)*4 + reg
  const int lr = lane >> 4, lc = lane & 15;
#pragma unroll
  for (int rb = 0; rb < 8; ++rb) {
#pragma unroll
    for (int r = 0; r < 4; ++r) {
      const int row = m0 + wm * 128 + rb * 16 + lr * 4 + r;
      float bM = 0.f;
      if (BIAS == 1) bM = bias[row];
      const long long ro = (long long)row * ldc;
#pragma unroll
      for (int cb = 0; cb < 4; ++cb) {
        const int col = n0 + wn * 64 + cb * 16 + lc;
        float v = acc[rb][cb][r] * scale;
        if (BIAS == 1) v += bM;
        if (BIAS == 2) v += bias[col];
        if constexpr (sizeof(OutT) == 2)
          C[ro + col] = f2h(v);
        else
          C[ro + col] = v;
      }
    }
  }
}

// fp32 -> fp16 elementwise cast, 4 elems/thread
__global__ void cast_f16(const float* __restrict__ in, short* __restrict__ out,
                         long long n) {
  long long i = ((long long)blockIdx.x * blockDim.x + threadIdx.x) * 4;
  if (i + 3 < n) {
    float4 v = *(const float4*)(in + i);
    halfx4s o;
    o[0] = f2h(v.x);
    o[1] = f2h(v.y);
    o[2] = f2h(v.z);
    o[3] = f2h(v.w);
    *(halfx4s*)(out + i) = o;
  }
}

// x[b][c][p] fp32 -> xT[b][p][c] fp16   (dim x dim per batch)
__global__ void transpose_cast(const float* __restrict__ x, short* __restrict__ xT,
                               int dim) {
  __shared__ float tile[64][65];
  const long long b = blockIdx.z;
  const float* xb = x + b * dim * (long long)dim;
  short* xTb = xT + b * dim * (long long)dim;
  const int c0 = blockIdx.y * 64, p0 = blockIdx.x * 64;
  const int tx = threadIdx.x & 63, ty = threadIdx.x >> 6;
#pragma unroll
  for (int i = 0; i < 64; i += 4)
    tile[ty + i][tx] = xb[(long long)(c0 + ty + i) * dim + p0 + tx];
  __syncthreads();
#pragma unroll
  for (int i = 0; i < 64; i += 4)
    xTb[(long long)(p0 + ty + i) * dim + c0 + tx] = f2h(tile[tx][ty + i]);
}

// row-wise softmax over 512 fp32 -> fp16; one 256-thread block per row
__global__ void softmax_rows(const float* __restrict__ S, short* __restrict__ P) {
  const long long row = blockIdx.x;
  const float* s = S + row * 512;
  const int t = threadIdx.x;
  float v0 = s[t], v1 = s[t + 256];
  float m = fmaxf(v0, v1);
  for (int o = 32; o; o >>= 1) m = fmaxf(m, __shfl_xor(m, o));
  __shared__ float red[4];
  const int wave = t >> 6, lane = t & 63;
  if (lane == 0) red[wave] = m;
  __syncthreads();
  m = fmaxf(fmaxf(red[0], red[1]), fmaxf(red[2], red[3]));
  float e0 = expf(v0 - m), e1 = expf(v1 - m);
  float sum = e0 + e1;
  for (int o = 32; o; o >>= 1) sum += __shfl_xor(sum, o);
  __syncthreads();
  if (lane == 0) red[wave] = sum;
  __syncthreads();
  sum = red[0] + red[1] + red[2] + red[3];
  const float inv = 1.0f / sum;
  short* p = P + row * 512;
  p[t] = f2h(e0 * inv);
  p[t + 256] = f2h(e1 * inv);
}

extern "C" void kernel_launch(void* const* d_in, const int* in_sizes, int n_in,
                              void* d_out, int out_size, void* d_ws, size_t ws_size,
                              hipStream_t stream) {
  const float* x    = (const float*)d_in[0];
  const float* Wqkv = (const float*)d_in[1];
  const float* bqkv = (const float*)d_in[2];
  const float* Wq   = (const float*)d_in[3];
  const float* bq   = (const float*)d_in[4];
  const float* Wk   = (const float*)d_in[5];
  const float* bk   = (const float*)d_in[6];
  const float* Wv   = (const float*)d_in[7];
  const float* bv   = (const float*)d_in[8];
  const float* Wout = (const float*)d_in[9];
  const float* bout = (const float*)d_in[10];
  float* out = (float*)d_out;

  const long long C = 4096, CPH = 512, P = 4096;

  size_t off = 0;
  auto alloc = [&](size_t bytes) -> char* {
    char* p = (char*)d_ws + off;
    off += (bytes + 255) & ~(size_t)255;
    return p;
  };
  short* Wqkv_b = (short*)alloc(3 * C * C * 2);   // reused as k2 after G1
  short* Wq_b   = (short*)alloc(C * C * 2);
  short* Wk_b   = (short*)alloc(C * C * 2);
  short* Wv_b   = (short*)alloc(C * C * 2);
  short* Wout_b = (short*)alloc(C * C * 2);
  short* xT     = (short*)alloc(2 * C * P * 2);   // reused as q2 after G1
  short* qkv    = (short*)alloc(2 * 3 * C * P * 2);
  short* v2T    = (short*)alloc(16 * C * CPH * 2);
  float* S      = (float*)alloc(16 * CPH * CPH * 4);
  short* Pm     = (short*)alloc(16 * CPH * CPH * 2);
  short* outT   = (short*)alloc(2 * C * P * 2);
  short* q2 = xT;
  short* k2 = Wqkv_b;
  if (off > ws_size) return;  // workspace too small: bail (will fail check loudly)

  // --- casts + transpose ---
  cast_f16<<<dim3((unsigned)(3 * C * C / 4 / 256)), 256, 0, stream>>>(Wqkv, Wqkv_b, 3 * C * C);
  cast_f16<<<dim3((unsigned)(C * C / 4 / 256)), 256, 0, stream>>>(Wq, Wq_b, C * C);
  cast_f16<<<dim3((unsigned)(C * C / 4 / 256)), 256, 0, stream>>>(Wk, Wk_b, C * C);
  cast_f16<<<dim3((unsigned)(C * C / 4 / 256)), 256, 0, stream>>>(Wv, Wv_b, C * C);
  cast_f16<<<dim3((unsigned)(C * C / 4 / 256)), 256, 0, stream>>>(Wout, Wout_b, C * C);
  transpose_cast<<<dim3(64, 64, 2), 256, 0, stream>>>(x, xT, 4096);

  // --- G1: qkv[b][o][p] = Wqkv . xT^T + bqkv  (M=12288,N=4096,K=4096, z=b) ---
  gemm256_nt<short, 1><<<dim3(16, 48, 2), 512, 0, stream>>>(
      Wqkv_b, xT, qkv, bqkv, 4096, 4096, 4096, 4096, 1.f,
      0, 0, C * P, 0, 3 * C * P, 0, 1);

  // --- G2: q2[b][hc][m] = qkv_q . Wq^T + bq(col) ---
  gemm256_nt<short, 2><<<dim3(16, 16, 2), 512, 0, stream>>>(
      qkv, Wq_b, q2, bq, 4096, 4096, 4096, 4096, 1.f,
      3 * C * P, 0, 0, 0, C * P, 0, 1);

  // --- G3: k2 = qkv_k . Wk^T + bk(col) ---
  gemm256_nt<short, 2><<<dim3(16, 16, 2), 512, 0, stream>>>(
      qkv + C * P, Wk_b, k2, bk, 4096, 4096, 4096, 4096, 1.f,
      3 * C * P, 0, 0, 0, C * P, 0, 1);

  // --- G4: v2T[z][m][d] = Wv . v_slice^T + bv(row)  (M=4096,N=512,K=4096, z=b*8+h) ---
  gemm256_nt<short, 1><<<dim3(2, 16, 16), 512, 0, stream>>>(
      Wv_b, qkv + 2 * C * P, v2T, bv, 4096, 4096, 4096, 512, 1.f,
      0, 0, 3 * C * P, CPH * P, 8 * C * CPH, C * CPH, 8);

  // --- G5: S[z][c][d] = 0.125 * q2_slice . k2_slice^T  (M=512,N=512,K=4096) ---
  gemm_nt<float, 0><<<dim3(4, 4, 16), 256, 0, stream>>>(
      q2, k2, S, nullptr, 4096, 4096, 4096, 512, 0.125f,
      C * P, CPH * P, C * P, CPH * P, 8 * CPH * CPH, CPH * CPH, 8);

  // --- softmax rows (16*512 rows of 512) ---
  softmax_rows<<<dim3(16 * 512), 256, 0, stream>>>(S, Pm);

  // --- G6: outT[b][m][h*512+c] = v2T_slice . P_slice^T  (M=4096,N=512,K=512) ---
  gemm_nt<short, 0><<<dim3(4, 32, 16), 256, 0, stream>>>(
      v2T, Pm, outT, nullptr, 512, 512, 512, 4096, 1.f,
      8 * C * CPH, C * CPH, 8 * CPH * CPH, CPH * CPH, C * P, 512, 8);

  // --- G7: out[b][o][p] = Wout . outT^T + bout(row)  (M=N=K=4096, fp32 out) ---
  gemm256_nt<float, 1><<<dim3(16, 16, 2), 512, 0, stream>>>(
      Wout_b, outT, out, bout, 4096, 4096, 4096, 4096, 1.f,
      0, 0, C * P, 0, C * P, 0, 1);
}

// Round 14
// 2533.613 us; speedup vs baseline: 1.0572x; 1.0572x over previous
//
#include <hip/hip_runtime.h>

#define DEVI __device__ __forceinline__

typedef __attribute__((ext_vector_type(8))) _Float16 halfx8;
typedef __attribute__((ext_vector_type(4))) short halfx4s;
typedef __attribute__((ext_vector_type(4))) float floatx4;

DEVI short f2h(float f) {
  _Float16 h = (_Float16)f;  // v_cvt_f16_f32, RNE
  return __builtin_bit_cast(short, h);
}

DEVI void gl_lds16(const void* g, void* l) {
  __builtin_amdgcn_global_load_lds(
      (const __attribute__((address_space(1))) void*)g,
      (__attribute__((address_space(3))) void*)l, 16, 0, 0);
}

// ---------------------------------------------------------------------------
// Generic NT GEMM (legacy 128x128 2-barrier structure) — kept for the small
// GEMMs G5/G6 (M or N == 512).
// ---------------------------------------------------------------------------
template <typename OutT, int BIAS>
__global__ __launch_bounds__(256) void gemm_nt(
    const short* __restrict__ A, const short* __restrict__ B,
    OutT* __restrict__ C, const float* __restrict__ bias,
    int K, int lda, int ldb, int ldc, float scale,
    long long a_s0, long long a_s1, long long b_s0, long long b_s1,
    long long c_s0, long long c_s1, int zdiv) {
  const int z = blockIdx.z;
  const int zb = z / zdiv, zh = z % zdiv;
  A += zb * a_s0 + zh * a_s1;
  B += zb * b_s0 + zh * b_s1;
  C += zb * c_s0 + zh * c_s1;

  const int m0 = blockIdx.y * 128, n0 = blockIdx.x * 128;
  const int t = threadIdx.x;
  const int wave = t >> 6, lane = t & 63;
  const int wm = wave >> 1, wn = wave & 1;

  __shared__ short As[128 * 32];
  __shared__ short Bs[128 * 32];

  floatx4 acc[4][4] = {};

  const char* ag = (const char*)(A + (long long)(m0 + (t >> 2)) * lda + (t & 3) * 8);
  const char* bg = (const char*)(B + (long long)(n0 + (t >> 2)) * ldb + (t & 3) * 8);
  const long long astep = (long long)lda * 2 * 64;
  const long long bstep = (long long)ldb * 2 * 64;
  short* asl = As + t * 8;
  short* bsl = Bs + t * 8;

  const int a_off = (wm * 64 + (lane & 15)) * 32 + (lane >> 4) * 8;
  const int b_off = (wn * 64 + (lane & 15)) * 32 + (lane >> 4) * 8;

  for (int kt = 0; kt < K; kt += 32) {
    __syncthreads();
    gl_lds16(ag, asl);
    gl_lds16(ag + astep, asl + 2048);
    gl_lds16(bg, bsl);
    gl_lds16(bg + bstep, bsl + 2048);
    ag += 64;
    bg += 64;
    __syncthreads();
    halfx8 af[4], bfr[4];
#pragma unroll
    for (int i = 0; i < 4; i++) af[i] = *(const halfx8*)(As + a_off + i * 16 * 32);
#pragma unroll
    for (int j = 0; j < 4; j++) bfr[j] = *(const halfx8*)(Bs + b_off + j * 16 * 32);
#pragma unroll
    for (int i = 0; i < 4; i++)
#pragma unroll
      for (int j = 0; j < 4; j++)
        acc[i][j] =
            __builtin_amdgcn_mfma_f32_16x16x32_f16(af[i], bfr[j], acc[i][j], 0, 0, 0);
  }

  const int lr = lane >> 4, lc = lane & 15;
#pragma unroll
  for (int i = 0; i < 4; i++) {
#pragma unroll
    for (int r = 0; r < 4; r++) {
      const int row = m0 + wm * 64 + i * 16 + lr * 4 + r;
      float bM = 0.f;
      if (BIAS == 1) bM = bias[row];
      const long long ro = (long long)row * ldc;
#pragma unroll
      for (int j = 0; j < 4; j++) {
        const int col = n0 + wn * 64 + j * 16 + lc;
        float v = acc[i][j][r] * scale;
        if (BIAS == 1) v += bM;
        if (BIAS == 2) v += bias[col];
        if constexpr (sizeof(OutT) == 2)
          C[ro + col] = f2h(v);
        else
          C[ro + col] = v;
      }
    }
  }
}

// ---------------------------------------------------------------------------
// 256x256 8-phase NT GEMM (T2+T3+T4+T5, m201-style). 512 thr = 8 waves
// (2M x 4N); wave owns 128x64; BK=64; nk = K/64 (even). LDS 128 KiB.
//
// v3 (measured r12): full-3-bit LDS swizzle stored_chunk = logical ^ (row&7)
// -> SQ_LDS_BANK_CONFLICT 7.55e7 -> 0, MfmaUtil 40.8 -> 46.3, G1 903 -> 824us.
// Remaining stall: FETCH 885MB vs ~160MB ideal (5.5x over-fetch). Linear
// dispatch round-robins XCDs -> each XCD L2 re-fetches the same A-panel ->
// stage loads miss L2 (~900cy) -> vmcnt(6) stalls at PH3 every K-step.
//
// v4: + T1 XCD-chunked swizzle. lin = y*gX+x; XCD (lin&7) owns contiguous
// chunk of q8 = nwg/8 tiles (y-major: ~2 A-panels = 4MB = one L2). Bijective
// since nwg%8==0 at all call sites (768/256/32/256); z-slices align (768%8=0)
// so A-panels shared across z within an XCD.
//
// vmcnt(6) ledger: PH3 entry has 14 outstanding ({B0,B1,A0}(j+1) staged in
// block j-1, A1(j+1)@PH0, {B0,B1,A0}(j+2)@PH1-3); vmcnt(6) drains exactly
// K-step j+1 before the seam barrier. Tail: vmcnt(0) when the issue stream
// thins. Every LDS slot overwrite issues after the phase whose lgkmcnt(0)
// + barrier drained that slot's last read (checked all 8 slots incl. seam).
// ---------------------------------------------------------------------------

#define LOAD_B(P)                                                            \
  _Pragma("unroll") for (int cb = 0; cb < 4; ++cb)                           \
      _Pragma("unroll") for (int ks = 0; ks < 2; ++ks)                       \
          bF[cb][ks] =                                                       \
              *(const halfx8*)(Br + (P)*16384 + cb * 1024 + ((ks * 32) ^ xm));

#define LOAD_A(P, DST, RBASE)                                                \
  _Pragma("unroll") for (int rb = 0; rb < 4; ++rb)                           \
      _Pragma("unroll") for (int ks = 0; ks < 2; ++ks)                       \
          DST[rb][ks] = *(const halfx8*)(Ar + (P)*16384 +                    \
                                         ((RBASE) + rb) * 1024 +             \
                                         ((ks * 32) ^ xm));

#define MFMA_Q(AF, RB0, CB0)                                                 \
  _Pragma("unroll") for (int rb = 0; rb < 4; ++rb)                           \
      _Pragma("unroll") for (int cb = 0; cb < 2; ++cb)                       \
          _Pragma("unroll") for (int ks = 0; ks < 2; ++ks)                   \
              acc[(RB0) + rb][(CB0) + cb] =                                  \
                  __builtin_amdgcn_mfma_f32_16x16x32_f16(                    \
                      AF[rb][ks], bF[(CB0) + cb][ks],                        \
                      acc[(RB0) + rb][(CB0) + cb], 0, 0, 0);

#define STAGE_A(PP, HH, JS)                                                  \
  {                                                                          \
    const char* s_ = Ag + (size_t)(HH) * (ldab << 7) + ((size_t)(JS) << 7);  \
    gl_lds16(s_, AsD + (PP)*16384 + (HH)*8192);                              \
    gl_lds16(s_ + (ldab << 6), AsD + (PP)*16384 + (HH)*8192 + 4096);         \
  }

#define STAGE_B(PP, HH, JS)                                                  \
  {                                                                          \
    const char* s_ = Bg + (size_t)(HH) * (ldbb << 7) + ((size_t)(JS) << 7);  \
    gl_lds16(s_, BsD + (PP)*16384 + (HH)*8192);                              \
    gl_lds16(s_ + (ldbb << 6), BsD + (PP)*16384 + (HH)*8192 + 4096);         \
  }

#define BLOCK256(P, J)                                                       \
  {                                                                          \
    halfx8 bF[4][2], aLo[4][2], aHi[4][2];                                   \
    /* PH0 */                                                                \
    LOAD_B(P);                                                               \
    LOAD_A(P, aLo, 0);                                                       \
    if ((J) + 1 < nk) STAGE_A((P) ^ 1, 1, (J) + 1);                          \
    __builtin_amdgcn_s_barrier();                                            \
    asm volatile("s_waitcnt lgkmcnt(0)" ::: "memory");                       \
    __builtin_amdgcn_s_setprio(1);                                           \
    MFMA_Q(aLo, 0, 0);                                                       \
    __builtin_amdgcn_s_setprio(0);                                           \
    __builtin_amdgcn_s_barrier();                                            \
    /* PH1 */                                                                \
    if ((J) + 2 < nk) STAGE_B(P, 0, (J) + 2);                                \
    __builtin_amdgcn_s_barrier();                                            \
    asm volatile("s_waitcnt lgkmcnt(0)" ::: "memory");                       \
    __builtin_amdgcn_s_setprio(1);                                           \
    MFMA_Q(aLo, 0, 2);                                                       \
    __builtin_amdgcn_s_setprio(0);                                           \
    __builtin_amdgcn_s_barrier();                                            \
    /* PH2 */                                                                \
    LOAD_A(P, aHi, 4);                                                       \
    if ((J) + 2 < nk) STAGE_B(P, 1, (J) + 2);                                \
    __builtin_amdgcn_s_barrier();                                            \
    asm volatile("s_waitcnt lgkmcnt(0)" ::: "memory");                       \
    __builtin_amdgcn_s_setprio(1);                                           \
    MFMA_Q(aHi, 4, 0);                                                       \
    __builtin_amdgcn_s_setprio(0);                                           \
    __builtin_amdgcn_s_barrier();                                            \
    /* PH3 */                                                                \
    if ((J) + 2 < nk) STAGE_A(P, 0, (J) + 2);                                \
    __builtin_amdgcn_s_barrier();                                            \
    asm volatile("s_waitcnt lgkmcnt(0)" ::: "memory");                       \
    __builtin_amdgcn_s_setprio(1);                                           \
    MFMA_Q(aHi, 4, 2);                                                       \
    __builtin_amdgcn_s_setprio(0);                                           \
    if ((J) + 2 < nk) {                                                      \
      asm volatile("s_waitcnt vmcnt(6)" ::: "memory");                       \
    } else {                                                                 \
      asm volatile("s_waitcnt vmcnt(0)" ::: "memory");                       \
    }                                                                        \
    __builtin_amdgcn_s_barrier();                                            \
  }

template <typename OutT, int BIAS>
__global__ __launch_bounds__(512, 2) void gemm256_nt(
    const short* __restrict__ A, const short* __restrict__ B,
    OutT* __restrict__ C, const float* __restrict__ bias,
    int K, int lda, int ldb, int ldc, float scale,
    long long a_s0, long long a_s1, long long b_s0, long long b_s1,
    long long c_s0, long long c_s1, int zdiv) {
  const int z = blockIdx.z;
  const int zb = z / zdiv, zh = z % zdiv;
  A += zb * a_s0 + zh * a_s1;
  B += zb * b_s0 + zh * b_s1;
  C += zb * c_s0 + zh * c_s1;

  // T1: XCD-chunked remap of (x,y). Requires (gX*gY)%8==0 (all call sites:
  // 768/256/32/256). XCD (lin&7) gets a contiguous y-major chunk of q8 tiles.
  const int gX = gridDim.x;
  const int nwg = gX * gridDim.y;
  const int lin = blockIdx.y * gX + blockIdx.x;
  const int q8 = nwg >> 3;
  const int swz = (lin & 7) * q8 + (lin >> 3);
  const int m0 = (swz / gX) * 256, n0 = (swz % gX) * 256;

  const int t = threadIdx.x;
  const int wave = t >> 6, lane = t & 63;
  const int wm = wave >> 2, wn = wave & 3;  // 2 x 4 wave grid

  __shared__ short As[2][2][8192];  // [dbuf][half(128 rows)][128*64]
  __shared__ short Bs[2][2][8192];

  floatx4 acc[8][4] = {};

  // --- staging: chunk t covers row t>>3, stored chunk t&7; logical chunk
  //     = (t&7) ^ ((t>>3)&7)  (inverse of stored = logical ^ (row&7)) ---
  const size_t ldab = (size_t)lda * 2, ldbb = (size_t)ldb * 2;
  const int rowt = t >> 3;
  const int kbt = (((t & 7) ^ ((t >> 3) & 7)) << 4);  // inverse swizzle, bytes
  const char* Ag = (const char*)A + (size_t)(m0 + rowt) * ldab + kbt;
  const char* Bg = (const char*)B + (size_t)(n0 + rowt) * ldbb + kbt;
  short* AsD = &As[0][0][0] + t * 8;
  short* BsD = &Bs[0][0][0] + t * 8;

  // --- read addresses (shorts): row*64 + stored_chunk*8 with
  //     stored_chunk = ((ks ^ lane_b2)<<2) | ((lane>>4) ^ (lane&3));
  //     ks term applied in LOAD macros as (ks*32) ^ xm ---
  const int laneR = ((lane & 15) << 6) | ((((lane >> 4) ^ (lane & 3))) << 3);
  const int xm = (lane & 4) << 3;
  const short* Ar = &As[0][0][0] + wm * 8192 + laneR;
  const short* Br = &Bs[0][0][0] + (wn >> 1) * 8192 + (wn & 1) * 4096 + laneR;

  const int nk = K >> 6;

  // prologue: stage K-step 0 fully, then B0,B1,A0 of K-step 1
  STAGE_B(0, 0, 0);
  STAGE_B(0, 1, 0);
  STAGE_A(0, 0, 0);
  STAGE_A(0, 1, 0);
  STAGE_B(1, 0, 1);
  STAGE_B(1, 1, 1);
  STAGE_A(1, 0, 1);
  asm volatile("s_waitcnt vmcnt(6)" ::: "memory");
  __builtin_amdgcn_s_barrier();

  for (int j = 0; j < nk; j += 2) {
    BLOCK256(0, j)
    BLOCK256(1, j + 1)
  }

  // epilogue: C/D layout col = lane&15, row = (lane>>4)*4 + reg
  const int lr = lane >> 4, lc = lane & 15;
#pragma unroll
  for (int rb = 0; rb < 8; ++rb) {
#pragma unroll
    for (int r = 0; r < 4; ++r) {
      const int row = m0 + wm * 128 + rb * 16 + lr * 4 + r;
      float bM = 0.f;
      if (BIAS == 1) bM = bias[row];
      const long long ro = (long long)row * ldc;
#pragma unroll
      for (int cb = 0; cb < 4; ++cb) {
        const int col = n0 + wn * 64 + cb * 16 + lc;
        float v = acc[rb][cb][r] * scale;
        if (BIAS == 1) v += bM;
        if (BIAS == 2) v += bias[col];
        if constexpr (sizeof(OutT) == 2)
          C[ro + col] = f2h(v);
        else
          C[ro + col] = v;
      }
    }
  }
}

// fp32 -> fp16 elementwise cast, 4 elems/thread
__global__ void cast_f16(const float* __restrict__ in, short* __restrict__ out,
                         long long n) {
  long long i = ((long long)blockIdx.x * blockDim.x + threadIdx.x) * 4;
  if (i + 3 < n) {
    float4 v = *(const float4*)(in + i);
    halfx4s o;
    o[0] = f2h(v.x);
    o[1] = f2h(v.y);
    o[2] = f2h(v.z);
    o[3] = f2h(v.w);
    *(halfx4s*)(out + i) = o;
  }
}

// x[b][c][p] fp32 -> xT[b][p][c] fp16   (dim x dim per batch)
__global__ void transpose_cast(const float* __restrict__ x, short* __restrict__ xT,
                               int dim) {
  __shared__ float tile[64][65];
  const long long b = blockIdx.z;
  const float* xb = x + b * dim * (long long)dim;
  short* xTb = xT + b * dim * (long long)dim;
  const int c0 = blockIdx.y * 64, p0 = blockIdx.x * 64;
  const int tx = threadIdx.x & 63, ty = threadIdx.x >> 6;
#pragma unroll
  for (int i = 0; i < 64; i += 4)
    tile[ty + i][tx] = xb[(long long)(c0 + ty + i) * dim + p0 + tx];
  __syncthreads();
#pragma unroll
  for (int i = 0; i < 64; i += 4)
    xTb[(long long)(p0 + ty + i) * dim + c0 + tx] = f2h(tile[tx][ty + i]);
}

// row-wise softmax over 512 fp32 -> fp16; one 256-thread block per row
__global__ void softmax_rows(const float* __restrict__ S, short* __restrict__ P) {
  const long long row = blockIdx.x;
  const float* s = S + row * 512;
  const int t = threadIdx.x;
  float v0 = s[t], v1 = s[t + 256];
  float m = fmaxf(v0, v1);
  for (int o = 32; o; o >>= 1) m = fmaxf(m, __shfl_xor(m, o));
  __shared__ float red[4];
  const int wave = t >> 6, lane = t & 63;
  if (lane == 0) red[wave] = m;
  __syncthreads();
  m = fmaxf(fmaxf(red[0], red[1]), fmaxf(red[2], red[3]));
  float e0 = expf(v0 - m), e1 = expf(v1 - m);
  float sum = e0 + e1;
  for (int o = 32; o; o >>= 1) sum += __shfl_xor(sum, o);
  __syncthreads();
  if (lane == 0) red[wave] = sum;
  __syncthreads();
  sum = red[0] + red[1] + red[2] + red[3];
  const float inv = 1.0f / sum;
  short* p = P + row * 512;
  p[t] = f2h(e0 * inv);
  p[t + 256] = f2h(e1 * inv);
}

extern "C" void kernel_launch(void* const* d_in, const int* in_sizes, int n_in,
                              void* d_out, int out_size, void* d_ws, size_t ws_size,
                              hipStream_t stream) {
  const float* x    = (const float*)d_in[0];
  const float* Wqkv = (const float*)d_in[1];
  const float* bqkv = (const float*)d_in[2];
  const float* Wq   = (const float*)d_in[3];
  const float* bq   = (const float*)d_in[4];
  const float* Wk   = (const float*)d_in[5];
  const float* bk   = (const float*)d_in[6];
  const float* Wv   = (const float*)d_in[7];
  const float* bv   = (const float*)d_in[8];
  const float* Wout = (const float*)d_in[9];
  const float* bout = (const float*)d_in[10];
  float* out = (float*)d_out;

  const long long C = 4096, CPH = 512, P = 4096;

  size_t off = 0;
  auto alloc = [&](size_t bytes) -> char* {
    char* p = (char*)d_ws + off;
    off += (bytes + 255) & ~(size_t)255;
    return p;
  };
  short* Wqkv_b = (short*)alloc(3 * C * C * 2);   // reused as k2 after G1
  short* Wq_b   = (short*)alloc(C * C * 2);
  short* Wk_b   = (short*)alloc(C * C * 2);
  short* Wv_b   = (short*)alloc(C * C * 2);
  short* Wout_b = (short*)alloc(C * C * 2);
  short* xT     = (short*)alloc(2 * C * P * 2);   // reused as q2 after G1
  short* qkv    = (short*)alloc(2 * 3 * C * P * 2);
  short* v2T    = (short*)alloc(16 * C * CPH * 2);
  float* S      = (float*)alloc(16 * CPH * CPH * 4);
  short* Pm     = (short*)alloc(16 * CPH * CPH * 2);
  short* outT   = (short*)alloc(2 * C * P * 2);
  short* q2 = xT;
  short* k2 = Wqkv_b;
  if (off > ws_size) return;  // workspace too small: bail (will fail check loudly)

  // --- casts + transpose ---
  cast_f16<<<dim3((unsigned)(3 * C * C / 4 / 256)), 256, 0, stream>>>(Wqkv, Wqkv_b, 3 * C * C);
  cast_f16<<<dim3((unsigned)(C * C / 4 / 256)), 256, 0, stream>>>(Wq, Wq_b, C * C);
  cast_f16<<<dim3((unsigned)(C * C / 4 / 256)), 256, 0, stream>>>(Wk, Wk_b, C * C);
  cast_f16<<<dim3((unsigned)(C * C / 4 / 256)), 256, 0, stream>>>(Wv, Wv_b, C * C);
  cast_f16<<<dim3((unsigned)(C * C / 4 / 256)), 256, 0, stream>>>(Wout, Wout_b, C * C);
  transpose_cast<<<dim3(64, 64, 2), 256, 0, stream>>>(x, xT, 4096);

  // --- G1: qkv[b][o][p] = Wqkv . xT^T + bqkv  (M=12288,N=4096,K=4096, z=b) ---
  gemm256_nt<short, 1><<<dim3(16, 48, 2), 512, 0, stream>>>(
      Wqkv_b, xT, qkv, bqkv, 4096, 4096, 4096, 4096, 1.f,
      0, 0, C * P, 0, 3 * C * P, 0, 1);

  // --- G2: q2[b][hc][m] = qkv_q . Wq^T + bq(col) ---
  gemm256_nt<short, 2><<<dim3(16, 16, 2), 512, 0, stream>>>(
      qkv, Wq_b, q2, bq, 4096, 4096, 4096, 4096, 1.f,
      3 * C * P, 0, 0, 0, C * P, 0, 1);

  // --- G3: k2 = qkv_k . Wk^T + bk(col) ---
  gemm256_nt<short, 2><<<dim3(16, 16, 2), 512, 0, stream>>>(
      qkv + C * P, Wk_b, k2, bk, 4096, 4096, 4096, 4096, 1.f,
      3 * C * P, 0, 0, 0, C * P, 0, 1);

  // --- G4: v2T[z][m][d] = Wv . v_slice^T + bv(row)  (M=4096,N=512,K=4096, z=b*8+h) ---
  gemm256_nt<short, 1><<<dim3(2, 16, 16), 512, 0, stream>>>(
      Wv_b, qkv + 2 * C * P, v2T, bv, 4096, 4096, 4096, 512, 1.f,
      0, 0, 3 * C * P, CPH * P, 8 * C * CPH, C * CPH, 8);

  // --- G5: S[z][c][d] = 0.125 * q2_slice . k2_slice^T  (M=512,N=512,K=4096) ---
  gemm_nt<float, 0><<<dim3(4, 4, 16), 256, 0, stream>>>(
      q2, k2, S, nullptr, 4096, 4096, 4096, 512, 0.125f,
      C * P, CPH * P, C * P, CPH * P, 8 * CPH * CPH, CPH * CPH, 8);

  // --- softmax rows (16*512 rows of 512) ---
  softmax_rows<<<dim3(16 * 512), 256, 0, stream>>>(S, Pm);

  // --- G6: outT[b][m][h*512+c] = v2T_slice . P_slice^T  (M=4096,N=512,K=512) ---
  gemm_nt<short, 0><<<dim3(4, 32, 16), 256, 0, stream>>>(
      v2T, Pm, outT, nullptr, 512, 512, 512, 4096, 1.f,
      8 * C * CPH, C * CPH, 8 * CPH * CPH, CPH * CPH, C * P, 512, 8);

  // --- G7: out[b][o][p] = Wout . outT^T + bout(row)  (M=N=K=4096, fp32 out) ---
  gemm256_nt<float, 1><<<dim3(16, 16, 2), 512, 0, stream>>>(
      Wout_b, outT, out, bout, 4096, 4096, 4096, 4096, 1.f,
      0, 0, C * P, 0, C * P, 0, 1);
}

// Round 16
// 2441.674 us; speedup vs baseline: 1.0970x; 1.0377x over previous
//
#include <hip/hip_runtime.h>

#define DEVI __device__ __forceinline__

typedef __attribute__((ext_vector_type(8))) _Float16 halfx8;
typedef __attribute__((ext_vector_type(4))) short halfx4s;
typedef __attribute__((ext_vector_type(4))) float floatx4;

DEVI short f2h(float f) {
  _Float16 h = (_Float16)f;  // v_cvt_f16_f32, RNE
  return __builtin_bit_cast(short, h);
}

DEVI void gl_lds16(const void* g, void* l) {
  __builtin_amdgcn_global_load_lds(
      (const __attribute__((address_space(1))) void*)g,
      (__attribute__((address_space(3))) void*)l, 16, 0, 0);
}

// ---------------------------------------------------------------------------
// Generic NT GEMM (legacy 128x128 2-barrier structure) — kept for the small
// GEMMs G5/G6 (M or N == 512).
// ---------------------------------------------------------------------------
template <typename OutT, int BIAS>
__global__ __launch_bounds__(256) void gemm_nt(
    const short* __restrict__ A, const short* __restrict__ B,
    OutT* __restrict__ C, const float* __restrict__ bias,
    int K, int lda, int ldb, int ldc, float scale,
    long long a_s0, long long a_s1, long long b_s0, long long b_s1,
    long long c_s0, long long c_s1, int zdiv) {
  const int z = blockIdx.z;
  const int zb = z / zdiv, zh = z % zdiv;
  A += zb * a_s0 + zh * a_s1;
  B += zb * b_s0 + zh * b_s1;
  C += zb * c_s0 + zh * c_s1;

  const int m0 = blockIdx.y * 128, n0 = blockIdx.x * 128;
  const int t = threadIdx.x;
  const int wave = t >> 6, lane = t & 63;
  const int wm = wave >> 1, wn = wave & 1;

  __shared__ short As[128 * 32];
  __shared__ short Bs[128 * 32];

  floatx4 acc[4][4] = {};

  const char* ag = (const char*)(A + (long long)(m0 + (t >> 2)) * lda + (t & 3) * 8);
  const char* bg = (const char*)(B + (long long)(n0 + (t >> 2)) * ldb + (t & 3) * 8);
  const long long astep = (long long)lda * 2 * 64;
  const long long bstep = (long long)ldb * 2 * 64;
  short* asl = As + t * 8;
  short* bsl = Bs + t * 8;

  const int a_off = (wm * 64 + (lane & 15)) * 32 + (lane >> 4) * 8;
  const int b_off = (wn * 64 + (lane & 15)) * 32 + (lane >> 4) * 8;

  for (int kt = 0; kt < K; kt += 32) {
    __syncthreads();
    gl_lds16(ag, asl);
    gl_lds16(ag + astep, asl + 2048);
    gl_lds16(bg, bsl);
    gl_lds16(bg + bstep, bsl + 2048);
    ag += 64;
    bg += 64;
    __syncthreads();
    halfx8 af[4], bfr[4];
#pragma unroll
    for (int i = 0; i < 4; i++) af[i] = *(const halfx8*)(As + a_off + i * 16 * 32);
#pragma unroll
    for (int j = 0; j < 4; j++) bfr[j] = *(const halfx8*)(Bs + b_off + j * 16 * 32);
#pragma unroll
    for (int i = 0; i < 4; i++)
#pragma unroll
      for (int j = 0; j < 4; j++)
        acc[i][j] =
            __builtin_amdgcn_mfma_f32_16x16x32_f16(af[i], bfr[j], acc[i][j], 0, 0, 0);
  }

  const int lr = lane >> 4, lc = lane & 15;
#pragma unroll
  for (int i = 0; i < 4; i++) {
#pragma unroll
    for (int r = 0; r < 4; r++) {
      const int row = m0 + wm * 64 + i * 16 + lr * 4 + r;
      float bM = 0.f;
      if (BIAS == 1) bM = bias[row];
      const long long ro = (long long)row * ldc;
#pragma unroll
      for (int j = 0; j < 4; j++) {
        const int col = n0 + wn * 64 + j * 16 + lc;
        float v = acc[i][j][r] * scale;
        if (BIAS == 1) v += bM;
        if (BIAS == 2) v += bias[col];
        if constexpr (sizeof(OutT) == 2)
          C[ro + col] = f2h(v);
        else
          C[ro + col] = v;
      }
    }
  }
}

// ---------------------------------------------------------------------------
// 256x256 NT GEMM, 4-phase / 4-barrier K-step (v5). 512 thr = 8 waves
// (2M x 4N); wave owns 128x64; BK=64; nk = K/64 (even). LDS 128 KiB.
//
// History: v3 full-3-bit LDS swizzle -> conflicts 7.55e7 -> 0 (G1 824us).
// v4 + XCD-chunked blockIdx swizzle -> G1 809us, FETCH unchanged (~886MB is
// L3-served L2 fill, not HBM stall). v5: barrier-audit — each phase was
// [reads; stage; BAR-A; lgkm; MFMA; BAR-B]; BAR-A is redundant in ALL phases:
//   * stage-vs-read WAR is covered by the PREVIOUS phase's BAR-B, since every
//     wave passes its own lgkm(0) (reads COMPLETE) before that barrier;
//   * PH1/PH3 have no reads, so their lgkm+BAR-A protected nothing;
//   * PH0 reads are protected by the seam vmcnt+bar.
// Slot-by-slot: A1->P^1 (idle buf); B0@PH1 after bar1 (all waves' bF reads
// done); B1@PH2 after bar2; A0@PH3 disjoint from aHi's A-half1. vmcnt ledger
// unchanged (stage issue order A1,B0,B1,A0; gl_lds counts vmcnt only).
// 8 -> 4 barriers/K-step, same registers, same fine stage interleave.
//
// vmcnt(6) ledger: PH3 entry has 14 outstanding ({B0,B1,A0}(j+1) staged in
// block j-1, A1(j+1)@PH0, {B0,B1,A0}(j+2)@PH1-3); vmcnt(6) drains exactly
// K-step j+1 before the seam barrier. Tail: vmcnt(0) when the stream thins.
// ---------------------------------------------------------------------------

#define LOAD_B(P)                                                            \
  _Pragma("unroll") for (int cb = 0; cb < 4; ++cb)                           \
      _Pragma("unroll") for (int ks = 0; ks < 2; ++ks)                       \
          bF[cb][ks] =                                                       \
              *(const halfx8*)(Br + (P)*16384 + cb * 1024 + ((ks * 32) ^ xm));

#define LOAD_A(P, DST, RBASE)                                                \
  _Pragma("unroll") for (int rb = 0; rb < 4; ++rb)                           \
      _Pragma("unroll") for (int ks = 0; ks < 2; ++ks)                       \
          DST[rb][ks] = *(const halfx8*)(Ar + (P)*16384 +                    \
                                         ((RBASE) + rb) * 1024 +             \
                                         ((ks * 32) ^ xm));

#define MFMA_Q(AF, RB0, CB0)                                                 \
  _Pragma("unroll") for (int rb = 0; rb < 4; ++rb)                           \
      _Pragma("unroll") for (int cb = 0; cb < 2; ++cb)                       \
          _Pragma("unroll") for (int ks = 0; ks < 2; ++ks)                   \
              acc[(RB0) + rb][(CB0) + cb] =                                  \
                  __builtin_amdgcn_mfma_f32_16x16x32_f16(                    \
                      AF[rb][ks], bF[(CB0) + cb][ks],                        \
                      acc[(RB0) + rb][(CB0) + cb], 0, 0, 0);

#define STAGE_A(PP, HH, JS)                                                  \
  {                                                                          \
    const char* s_ = Ag + (size_t)(HH) * (ldab << 7) + ((size_t)(JS) << 7);  \
    gl_lds16(s_, AsD + (PP)*16384 + (HH)*8192);                              \
    gl_lds16(s_ + (ldab << 6), AsD + (PP)*16384 + (HH)*8192 + 4096);         \
  }

#define STAGE_B(PP, HH, JS)                                                  \
  {                                                                          \
    const char* s_ = Bg + (size_t)(HH) * (ldbb << 7) + ((size_t)(JS) << 7);  \
    gl_lds16(s_, BsD + (PP)*16384 + (HH)*8192);                              \
    gl_lds16(s_ + (ldbb << 6), BsD + (PP)*16384 + (HH)*8192 + 4096);         \
  }

#define BLOCK256(P, J)                                                       \
  {                                                                          \
    halfx8 bF[4][2], aLo[4][2], aHi[4][2];                                   \
    /* PH0: read bF+aLo, stage A1(j+1)->P^1, MFMA aLo x cb01 */              \
    LOAD_B(P);                                                               \
    LOAD_A(P, aLo, 0);                                                       \
    if ((J) + 1 < nk) STAGE_A((P) ^ 1, 1, (J) + 1);                          \
    asm volatile("s_waitcnt lgkmcnt(0)" ::: "memory");                       \
    __builtin_amdgcn_s_setprio(1);                                           \
    MFMA_Q(aLo, 0, 0);                                                       \
    __builtin_amdgcn_s_setprio(0);                                           \
    __builtin_amdgcn_s_barrier();                                            \
    /* PH1: stage B0(j+2), MFMA aLo x cb23 */                                \
    if ((J) + 2 < nk) STAGE_B(P, 0, (J) + 2);                                \
    __builtin_amdgcn_s_setprio(1);                                           \
    MFMA_Q(aLo, 0, 2);                                                       \
    __builtin_amdgcn_s_setprio(0);                                           \
    __builtin_amdgcn_s_barrier();                                            \
    /* PH2: read aHi, stage B1(j+2), MFMA aHi x cb01 */                      \
    LOAD_A(P, aHi, 4);                                                       \
    if ((J) + 2 < nk) STAGE_B(P, 1, (J) + 2);                                \
    asm volatile("s_waitcnt lgkmcnt(0)" ::: "memory");                       \
    __builtin_amdgcn_s_setprio(1);                                           \
    MFMA_Q(aHi, 4, 0);                                                       \
    __builtin_amdgcn_s_setprio(0);                                           \
    __builtin_amdgcn_s_barrier();                                            \
    /* PH3: stage A0(j+2), MFMA aHi x cb23, counted vmcnt, seam bar */       \
    if ((J) + 2 < nk) STAGE_A(P, 0, (J) + 2);                                \
    __builtin_amdgcn_s_setprio(1);                                           \
    MFMA_Q(aHi, 4, 2);                                                       \
    __builtin_amdgcn_s_setprio(0);                                           \
    if ((J) + 2 < nk) {                                                      \
      asm volatile("s_waitcnt vmcnt(6)" ::: "memory");                       \
    } else {                                                                 \
      asm volatile("s_waitcnt vmcnt(0)" ::: "memory");                       \
    }                                                                        \
    __builtin_amdgcn_s_barrier();                                            \
  }

template <typename OutT, int BIAS>
__global__ __launch_bounds__(512, 2) void gemm256_nt(
    const short* __restrict__ A, const short* __restrict__ B,
    OutT* __restrict__ C, const float* __restrict__ bias,
    int K, int lda, int ldb, int ldc, float scale,
    long long a_s0, long long a_s1, long long b_s0, long long b_s1,
    long long c_s0, long long c_s1, int zdiv) {
  const int z = blockIdx.z;
  const int zb = z / zdiv, zh = z % zdiv;
  A += zb * a_s0 + zh * a_s1;
  B += zb * b_s0 + zh * b_s1;
  C += zb * c_s0 + zh * c_s1;

  // T1: XCD-chunked remap of (x,y). Requires (gX*gY)%8==0 (all call sites:
  // 768/256/32/256). XCD (lin&7) gets a contiguous y-major chunk of q8 tiles.
  const int gX = gridDim.x;
  const int nwg = gX * gridDim.y;
  const int lin = blockIdx.y * gX + blockIdx.x;
  const int q8 = nwg >> 3;
  const int swz = (lin & 7) * q8 + (lin >> 3);
  const int m0 = (swz / gX) * 256, n0 = (swz % gX) * 256;

  const int t = threadIdx.x;
  const int wave = t >> 6, lane = t & 63;
  const int wm = wave >> 2, wn = wave & 3;  // 2 x 4 wave grid

  __shared__ short As[2][2][8192];  // [dbuf][half(128 rows)][128*64]
  __shared__ short Bs[2][2][8192];

  floatx4 acc[8][4] = {};

  // --- staging: chunk t covers row t>>3, stored chunk t&7; logical chunk
  //     = (t&7) ^ ((t>>3)&7)  (inverse of stored = logical ^ (row&7)) ---
  const size_t ldab = (size_t)lda * 2, ldbb = (size_t)ldb * 2;
  const int rowt = t >> 3;
  const int kbt = (((t & 7) ^ ((t >> 3) & 7)) << 4);  // inverse swizzle, bytes
  const char* Ag = (const char*)A + (size_t)(m0 + rowt) * ldab + kbt;
  const char* Bg = (const char*)B + (size_t)(n0 + rowt) * ldbb + kbt;
  short* AsD = &As[0][0][0] + t * 8;
  short* BsD = &Bs[0][0][0] + t * 8;

  // --- read addresses (shorts): row*64 + stored_chunk*8 with
  //     stored_chunk = ((ks ^ lane_b2)<<2) | ((lane>>4) ^ (lane&3));
  //     ks term applied in LOAD macros as (ks*32) ^ xm ---
  const int laneR = ((lane & 15) << 6) | ((((lane >> 4) ^ (lane & 3))) << 3);
  const int xm = (lane & 4) << 3;
  const short* Ar = &As[0][0][0] + wm * 8192 + laneR;
  const short* Br = &Bs[0][0][0] + (wn >> 1) * 8192 + (wn & 1) * 4096 + laneR;

  const int nk = K >> 6;

  // prologue: stage K-step 0 fully, then B0,B1,A0 of K-step 1
  STAGE_B(0, 0, 0);
  STAGE_B(0, 1, 0);
  STAGE_A(0, 0, 0);
  STAGE_A(0, 1, 0);
  STAGE_B(1, 0, 1);
  STAGE_B(1, 1, 1);
  STAGE_A(1, 0, 1);
  asm volatile("s_waitcnt vmcnt(6)" ::: "memory");
  __builtin_amdgcn_s_barrier();

  for (int j = 0; j < nk; j += 2) {
    BLOCK256(0, j)
    BLOCK256(1, j + 1)
  }

  // epilogue: C/D layout col = lane&15, row = (lane>>4)*4 + reg
  const int lr = lane >> 4, lc = lane & 15;
#pragma unroll
  for (int rb = 0; rb < 8; ++rb) {
#pragma unroll
    for (int r = 0; r < 4; ++r) {
      const int row = m0 + wm * 128 + rb * 16 + lr * 4 + r;
      float bM = 0.f;
      if (BIAS == 1) bM = bias[row];
      const long long ro = (long long)row * ldc;
#pragma unroll
      for (int cb = 0; cb < 4; ++cb) {
        const int col = n0 + wn * 64 + cb * 16 + lc;
        float v = acc[rb][cb][r] * scale;
        if (BIAS == 1) v += bM;
        if (BIAS == 2) v += bias[col];
        if constexpr (sizeof(OutT) == 2)
          C[ro + col] = f2h(v);
        else
          C[ro + col] = v;
      }
    }
  }
}

// fp32 -> fp16 elementwise cast, 4 elems/thread
__global__ void cast_f16(const float* __restrict__ in, short* __restrict__ out,
                         long long n) {
  long long i = ((long long)blockIdx.x * blockDim.x + threadIdx.x) * 4;
  if (i + 3 < n) {
    float4 v = *(const float4*)(in + i);
    halfx4s o;
    o[0] = f2h(v.x);
    o[1] = f2h(v.y);
    o[2] = f2h(v.z);
    o[3] = f2h(v.w);
    *(halfx4s*)(out + i) = o;
  }
}

// x[b][c][p] fp32 -> xT[b][p][c] fp16   (dim x dim per batch)
__global__ void transpose_cast(const float* __restrict__ x, short* __restrict__ xT,
                               int dim) {
  __shared__ float tile[64][65];
  const long long b = blockIdx.z;
  const float* xb = x + b * dim * (long long)dim;
  short* xTb = xT + b * dim * (long long)dim;
  const int c0 = blockIdx.y * 64, p0 = blockIdx.x * 64;
  const int tx = threadIdx.x & 63, ty = threadIdx.x >> 6;
#pragma unroll
  for (int i = 0; i < 64; i += 4)
    tile[ty + i][tx] = xb[(long long)(c0 + ty + i) * dim + p0 + tx];
  __syncthreads();
#pragma unroll
  for (int i = 0; i < 64; i += 4)
    xTb[(long long)(p0 + ty + i) * dim + c0 + tx] = f2h(tile[tx][ty + i]);
}

// row-wise softmax over 512 fp32 -> fp16; one 256-thread block per row
__global__ void softmax_rows(const float* __restrict__ S, short* __restrict__ P) {
  const long long row = blockIdx.x;
  const float* s = S + row * 512;
  const int t = threadIdx.x;
  float v0 = s[t], v1 = s[t + 256];
  float m = fmaxf(v0, v1);
  for (int o = 32; o; o >>= 1) m = fmaxf(m, __shfl_xor(m, o));
  __shared__ float red[4];
  const int wave = t >> 6, lane = t & 63;
  if (lane == 0) red[wave] = m;
  __syncthreads();
  m = fmaxf(fmaxf(red[0], red[1]), fmaxf(red[2], red[3]));
  float e0 = expf(v0 - m), e1 = expf(v1 - m);
  float sum = e0 + e1;
  for (int o = 32; o; o >>= 1) sum += __shfl_xor(sum, o);
  __syncthreads();
  if (lane == 0) red[wave] = sum;
  __syncthreads();
  sum = red[0] + red[1] + red[2] + red[3];
  const float inv = 1.0f / sum;
  short* p = P + row * 512;
  p[t] = f2h(e0 * inv);
  p[t + 256] = f2h(e1 * inv);
}

extern "C" void kernel_launch(void* const* d_in, const int* in_sizes, int n_in,
                              void* d_out, int out_size, void* d_ws, size_t ws_size,
                              hipStream_t stream) {
  const float* x    = (const float*)d_in[0];
  const float* Wqkv = (const float*)d_in[1];
  const float* bqkv = (const float*)d_in[2];
  const float* Wq   = (const float*)d_in[3];
  const float* bq   = (const float*)d_in[4];
  const float* Wk   = (const float*)d_in[5];
  const float* bk   = (const float*)d_in[6];
  const float* Wv   = (const float*)d_in[7];
  const float* bv   = (const float*)d_in[8];
  const float* Wout = (const float*)d_in[9];
  const float* bout = (const float*)d_in[10];
  float* out = (float*)d_out;

  const long long C = 4096, CPH = 512, P = 4096;

  size_t off = 0;
  auto alloc = [&](size_t bytes) -> char* {
    char* p = (char*)d_ws + off;
    off += (bytes + 255) & ~(size_t)255;
    return p;
  };
  short* Wqkv_b = (short*)alloc(3 * C * C * 2);   // reused as k2 after G1
  short* Wq_b   = (short*)alloc(C * C * 2);
  short* Wk_b   = (short*)alloc(C * C * 2);
  short* Wv_b   = (short*)alloc(C * C * 2);
  short* Wout_b = (short*)alloc(C * C * 2);
  short* xT     = (short*)alloc(2 * C * P * 2);   // reused as q2 after G1
  short* qkv    = (short*)alloc(2 * 3 * C * P * 2);
  short* v2T    = (short*)alloc(16 * C * CPH * 2);
  float* S      = (float*)alloc(16 * CPH * CPH * 4);
  short* Pm     = (short*)alloc(16 * CPH * CPH * 2);
  short* outT   = (short*)alloc(2 * C * P * 2);
  short* q2 = xT;
  short* k2 = Wqkv_b;
  if (off > ws_size) return;  // workspace too small: bail (will fail check loudly)

  // --- casts + transpose ---
  cast_f16<<<dim3((unsigned)(3 * C * C / 4 / 256)), 256, 0, stream>>>(Wqkv, Wqkv_b, 3 * C * C);
  cast_f16<<<dim3((unsigned)(C * C / 4 / 256)), 256, 0, stream>>>(Wq, Wq_b, C * C);
  cast_f16<<<dim3((unsigned)(C * C / 4 / 256)), 256, 0, stream>>>(Wk, Wk_b, C * C);
  cast_f16<<<dim3((unsigned)(C * C / 4 / 256)), 256, 0, stream>>>(Wv, Wv_b, C * C);
  cast_f16<<<dim3((unsigned)(C * C / 4 / 256)), 256, 0, stream>>>(Wout, Wout_b, C * C);
  transpose_cast<<<dim3(64, 64, 2), 256, 0, stream>>>(x, xT, 4096);

  // --- G1: qkv[b][o][p] = Wqkv . xT^T + bqkv  (M=12288,N=4096,K=4096, z=b) ---
  gemm256_nt<short, 1><<<dim3(16, 48, 2), 512, 0, stream>>>(
      Wqkv_b, xT, qkv, bqkv, 4096, 4096, 4096, 4096, 1.f,
      0, 0, C * P, 0, 3 * C * P, 0, 1);

  // --- G2: q2[b][hc][m] = qkv_q . Wq^T + bq(col) ---
  gemm256_nt<short, 2><<<dim3(16, 16, 2), 512, 0, stream>>>(
      qkv, Wq_b, q2, bq, 4096, 4096, 4096, 4096, 1.f,
      3 * C * P, 0, 0, 0, C * P, 0, 1);

  // --- G3: k2 = qkv_k . Wk^T + bk(col) ---
  gemm256_nt<short, 2><<<dim3(16, 16, 2), 512, 0, stream>>>(
      qkv + C * P, Wk_b, k2, bk, 4096, 4096, 4096, 4096, 1.f,
      3 * C * P, 0, 0, 0, C * P, 0, 1);

  // --- G4: v2T[z][m][d] = Wv . v_slice^T + bv(row)  (M=4096,N=512,K=4096, z=b*8+h) ---
  gemm256_nt<short, 1><<<dim3(2, 16, 16), 512, 0, stream>>>(
      Wv_b, qkv + 2 * C * P, v2T, bv, 4096, 4096, 4096, 512, 1.f,
      0, 0, 3 * C * P, CPH * P, 8 * C * CPH, C * CPH, 8);

  // --- G5: S[z][c][d] = 0.125 * q2_slice . k2_slice^T  (M=512,N=512,K=4096) ---
  gemm_nt<float, 0><<<dim3(4, 4, 16), 256, 0, stream>>>(
      q2, k2, S, nullptr, 4096, 4096, 4096, 512, 0.125f,
      C * P, CPH * P, C * P, CPH * P, 8 * CPH * CPH, CPH * CPH, 8);

  // --- softmax rows (16*512 rows of 512) ---
  softmax_rows<<<dim3(16 * 512), 256, 0, stream>>>(S, Pm);

  // --- G6: outT[b][m][h*512+c] = v2T_slice . P_slice^T  (M=4096,N=512,K=512) ---
  gemm_nt<short, 0><<<dim3(4, 32, 16), 256, 0, stream>>>(
      v2T, Pm, outT, nullptr, 512, 512, 512, 4096, 1.f,
      8 * C * CPH, C * CPH, 8 * CPH * CPH, CPH * CPH, C * P, 512, 8);

  // --- G7: out[b][o][p] = Wout . outT^T + bout(row)  (M=N=K=4096, fp32 out) ---
  gemm256_nt<float, 1><<<dim3(16, 16, 2), 512, 0, stream>>>(
      Wout_b, outT, out, bout, 4096, 4096, 4096, 4096, 1.f,
      0, 0, C * P, 0, C * P, 0, 1);
}

// Round 18
// 2350.156 us; speedup vs baseline: 1.1397x; 1.0389x over previous
//
#include <hip/hip_runtime.h>

#define DEVI __device__ __forceinline__

typedef __attribute__((ext_vector_type(8))) _Float16 halfx8;
typedef __attribute__((ext_vector_type(4))) short halfx4s;
typedef __attribute__((ext_vector_type(4))) float floatx4;

DEVI short f2h(float f) {
  _Float16 h = (_Float16)f;  // v_cvt_f16_f32, RNE
  return __builtin_bit_cast(short, h);
}

DEVI void gl_lds16(const void* g, void* l) {
  __builtin_amdgcn_global_load_lds(
      (const __attribute__((address_space(1))) void*)g,
      (__attribute__((address_space(3))) void*)l, 16, 0, 0);
}

// ---------------------------------------------------------------------------
// Generic NT GEMM (legacy 128x128 2-barrier structure) — kept for the small
// GEMMs G5/G6 (M or N == 512).
// ---------------------------------------------------------------------------
template <typename OutT, int BIAS>
__global__ __launch_bounds__(256) void gemm_nt(
    const short* __restrict__ A, const short* __restrict__ B,
    OutT* __restrict__ C, const float* __restrict__ bias,
    int K, int lda, int ldb, int ldc, float scale,
    long long a_s0, long long a_s1, long long b_s0, long long b_s1,
    long long c_s0, long long c_s1, int zdiv) {
  const int z = blockIdx.z;
  const int zb = z / zdiv, zh = z % zdiv;
  A += zb * a_s0 + zh * a_s1;
  B += zb * b_s0 + zh * b_s1;
  C += zb * c_s0 + zh * c_s1;

  const int m0 = blockIdx.y * 128, n0 = blockIdx.x * 128;
  const int t = threadIdx.x;
  const int wave = t >> 6, lane = t & 63;
  const int wm = wave >> 1, wn = wave & 1;

  __shared__ short As[128 * 32];
  __shared__ short Bs[128 * 32];

  floatx4 acc[4][4] = {};

  const char* ag = (const char*)(A + (long long)(m0 + (t >> 2)) * lda + (t & 3) * 8);
  const char* bg = (const char*)(B + (long long)(n0 + (t >> 2)) * ldb + (t & 3) * 8);
  const long long astep = (long long)lda * 2 * 64;
  const long long bstep = (long long)ldb * 2 * 64;
  short* asl = As + t * 8;
  short* bsl = Bs + t * 8;

  const int a_off = (wm * 64 + (lane & 15)) * 32 + (lane >> 4) * 8;
  const int b_off = (wn * 64 + (lane & 15)) * 32 + (lane >> 4) * 8;

  for (int kt = 0; kt < K; kt += 32) {
    __syncthreads();
    gl_lds16(ag, asl);
    gl_lds16(ag + astep, asl + 2048);
    gl_lds16(bg, bsl);
    gl_lds16(bg + bstep, bsl + 2048);
    ag += 64;
    bg += 64;
    __syncthreads();
    halfx8 af[4], bfr[4];
#pragma unroll
    for (int i = 0; i < 4; i++) af[i] = *(const halfx8*)(As + a_off + i * 16 * 32);
#pragma unroll
    for (int j = 0; j < 4; j++) bfr[j] = *(const halfx8*)(Bs + b_off + j * 16 * 32);
#pragma unroll
    for (int i = 0; i < 4; i++)
#pragma unroll
      for (int j = 0; j < 4; j++)
        acc[i][j] =
            __builtin_amdgcn_mfma_f32_16x16x32_f16(af[i], bfr[j], acc[i][j], 0, 0, 0);
  }

  const int lr = lane >> 4, lc = lane & 15;
#pragma unroll
  for (int i = 0; i < 4; i++) {
#pragma unroll
    for (int r = 0; r < 4; r++) {
      const int row = m0 + wm * 64 + i * 16 + lr * 4 + r;
      float bM = 0.f;
      if (BIAS == 1) bM = bias[row];
      const long long ro = (long long)row * ldc;
#pragma unroll
      for (int j = 0; j < 4; j++) {
        const int col = n0 + wn * 64 + j * 16 + lc;
        float v = acc[i][j][r] * scale;
        if (BIAS == 1) v += bM;
        if (BIAS == 2) v += bias[col];
        if constexpr (sizeof(OutT) == 2)
          C[ro + col] = f2h(v);
        else
          C[ro + col] = v;
      }
    }
  }
}

// ---------------------------------------------------------------------------
// 256x256 NT GEMM, 2-barrier K-step (v6). 512 thr = 8 waves (2M x 4N);
// wave owns 128x64; BK=64; nk = K/64 (even). LDS 128 KiB, 1 block/CU.
//
// History: v3 LDS swizzle -> conflicts 0 (824us G1). v4 XCD swizzle (809).
// v5 4-barrier (744, MfmaUtil 51%). v6: read the ENTIRE per-wave working set
// (bF + aLo + aHi = 24 x b128) upfront; after lgkm(0) every wave's buf-P data
// is in registers, so ONE barrier (bar0) makes all (J+2) stages into P safe
// (B0/B1/A0 each overwrite data already consumed by all waves). Only the
// seam barrier remains for the dbuf handoff. 4 -> 2 barriers/K-step.
//
// Hazards: A1(J+1)->P^1 (other buf; P^1's block-J-1 readers drained at
// seam(J-1)) ; {B0,B1,A0}(J+2)->P after bar0 (all waves passed lgkm(0):
// every P read complete) ; A1(J+2)->P half1 staged by block J+1 after
// seam(J) (aHi reads done). vmcnt(6) ledger: entering steady state 6
// outstanding ({B0B1A0}(J+1)); +2 (A1(J+1)) +6 ((J+2)) = 14; oldest 8 =
// K-step J+1 exactly -> vmcnt(6) at seam guarantees J+1 landed, leaves 6.
// Tail: J+2==nk block issues only A1(J+1) (8 outstanding) -> vmcnt(0);
// last block issues none -> vmcnt(0) no-op. Prologue: 8+6 staged, vmcnt(6).
// ---------------------------------------------------------------------------

#define LOAD_B(P)                                                            \
  _Pragma("unroll") for (int cb = 0; cb < 4; ++cb)                           \
      _Pragma("unroll") for (int ks = 0; ks < 2; ++ks)                       \
          bF[cb][ks] =                                                       \
              *(const halfx8*)(Br + (P)*16384 + cb * 1024 + ((ks * 32) ^ xm));

#define LOAD_A(P, DST, RBASE)                                                \
  _Pragma("unroll") for (int rb = 0; rb < 4; ++rb)                           \
      _Pragma("unroll") for (int ks = 0; ks < 2; ++ks)                       \
          DST[rb][ks] = *(const halfx8*)(Ar + (P)*16384 +                    \
                                         ((RBASE) + rb) * 1024 +             \
                                         ((ks * 32) ^ xm));

#define MFMA_Q(AF, RB0, CB0)                                                 \
  _Pragma("unroll") for (int rb = 0; rb < 4; ++rb)                           \
      _Pragma("unroll") for (int cb = 0; cb < 2; ++cb)                       \
          _Pragma("unroll") for (int ks = 0; ks < 2; ++ks)                   \
              acc[(RB0) + rb][(CB0) + cb] =                                  \
                  __builtin_amdgcn_mfma_f32_16x16x32_f16(                    \
                      AF[rb][ks], bF[(CB0) + cb][ks],                        \
                      acc[(RB0) + rb][(CB0) + cb], 0, 0, 0);

#define STAGE_A(PP, HH, JS)                                                  \
  {                                                                          \
    const char* s_ = Ag + (size_t)(HH) * (ldab << 7) + ((size_t)(JS) << 7);  \
    gl_lds16(s_, AsD + (PP)*16384 + (HH)*8192);                              \
    gl_lds16(s_ + (ldab << 6), AsD + (PP)*16384 + (HH)*8192 + 4096);         \
  }

#define STAGE_B(PP, HH, JS)                                                  \
  {                                                                          \
    const char* s_ = Bg + (size_t)(HH) * (ldbb << 7) + ((size_t)(JS) << 7);  \
    gl_lds16(s_, BsD + (PP)*16384 + (HH)*8192);                              \
    gl_lds16(s_ + (ldbb << 6), BsD + (PP)*16384 + (HH)*8192 + 4096);         \
  }

#define BLOCK256(P, J)                                                       \
  {                                                                          \
    halfx8 bF[4][2], aLo[4][2], aHi[4][2];                                   \
    /* PH0: ALL reads from buf P; stage A1(J+1)->P^1; MFMA aLo full row */   \
    LOAD_B(P);                                                               \
    LOAD_A(P, aLo, 0);                                                       \
    LOAD_A(P, aHi, 4);                                                       \
    if ((J) + 1 < nk) STAGE_A((P) ^ 1, 1, (J) + 1);                          \
    asm volatile("s_waitcnt lgkmcnt(0)" ::: "memory");                       \
    __builtin_amdgcn_s_setprio(1);                                           \
    MFMA_Q(aLo, 0, 0);                                                       \
    MFMA_Q(aLo, 0, 2);                                                       \
    __builtin_amdgcn_s_setprio(0);                                           \
    __builtin_amdgcn_s_barrier();                                            \
    /* PH1: stage (J+2) into P (safe: all P reads in regs); MFMA aHi */      \
    if ((J) + 2 < nk) {                                                      \
      STAGE_B(P, 0, (J) + 2);                                                \
      STAGE_B(P, 1, (J) + 2);                                                \
      STAGE_A(P, 0, (J) + 2);                                                \
    }                                                                        \
    __builtin_amdgcn_s_setprio(1);                                           \
    MFMA_Q(aHi, 4, 0);                                                       \
    MFMA_Q(aHi, 4, 2);                                                       \
    __builtin_amdgcn_s_setprio(0);                                           \
    if ((J) + 2 < nk) {                                                      \
      asm volatile("s_waitcnt vmcnt(6)" ::: "memory");                       \
    } else {                                                                 \
      asm volatile("s_waitcnt vmcnt(0)" ::: "memory");                       \
    }                                                                        \
    __builtin_amdgcn_s_barrier();                                            \
  }

template <typename OutT, int BIAS>
__global__ __launch_bounds__(512, 2) void gemm256_nt(
    const short* __restrict__ A, const short* __restrict__ B,
    OutT* __restrict__ C, const float* __restrict__ bias,
    int K, int lda, int ldb, int ldc, float scale,
    long long a_s0, long long a_s1, long long b_s0, long long b_s1,
    long long c_s0, long long c_s1, int zdiv) {
  const int z = blockIdx.z;
  const int zb = z / zdiv, zh = z % zdiv;
  A += zb * a_s0 + zh * a_s1;
  B += zb * b_s0 + zh * b_s1;
  C += zb * c_s0 + zh * c_s1;

  // T1: XCD-chunked remap of (x,y). Requires (gX*gY)%8==0 (all call sites:
  // 768/256/32/256). XCD (lin&7) gets a contiguous y-major chunk of q8 tiles.
  const int gX = gridDim.x;
  const int nwg = gX * gridDim.y;
  const int lin = blockIdx.y * gX + blockIdx.x;
  const int q8 = nwg >> 3;
  const int swz = (lin & 7) * q8 + (lin >> 3);
  const int m0 = (swz / gX) * 256, n0 = (swz % gX) * 256;

  const int t = threadIdx.x;
  const int wave = t >> 6, lane = t & 63;
  const int wm = wave >> 2, wn = wave & 3;  // 2 x 4 wave grid

  __shared__ short As[2][2][8192];  // [dbuf][half(128 rows)][128*64]
  __shared__ short Bs[2][2][8192];

  floatx4 acc[8][4] = {};

  // --- staging: chunk t covers row t>>3, stored chunk t&7; logical chunk
  //     = (t&7) ^ ((t>>3)&7)  (inverse of stored = logical ^ (row&7)) ---
  const size_t ldab = (size_t)lda * 2, ldbb = (size_t)ldb * 2;
  const int rowt = t >> 3;
  const int kbt = (((t & 7) ^ ((t >> 3) & 7)) << 4);  // inverse swizzle, bytes
  const char* Ag = (const char*)A + (size_t)(m0 + rowt) * ldab + kbt;
  const char* Bg = (const char*)B + (size_t)(n0 + rowt) * ldbb + kbt;
  short* AsD = &As[0][0][0] + t * 8;
  short* BsD = &Bs[0][0][0] + t * 8;

  // --- read addresses (shorts): row*64 + stored_chunk*8 with
  //     stored_chunk = ((ks ^ lane_b2)<<2) | ((lane>>4) ^ (lane&3));
  //     ks term applied in LOAD macros as (ks*32) ^ xm ---
  const int laneR = ((lane & 15) << 6) | ((((lane >> 4) ^ (lane & 3))) << 3);
  const int xm = (lane & 4) << 3;
  const short* Ar = &As[0][0][0] + wm * 8192 + laneR;
  const short* Br = &Bs[0][0][0] + (wn >> 1) * 8192 + (wn & 1) * 4096 + laneR;

  const int nk = K >> 6;

  // prologue: stage K-step 0 fully, then B0,B1,A0 of K-step 1
  STAGE_B(0, 0, 0);
  STAGE_B(0, 1, 0);
  STAGE_A(0, 0, 0);
  STAGE_A(0, 1, 0);
  STAGE_B(1, 0, 1);
  STAGE_B(1, 1, 1);
  STAGE_A(1, 0, 1);
  asm volatile("s_waitcnt vmcnt(6)" ::: "memory");
  __builtin_amdgcn_s_barrier();

  for (int j = 0; j < nk; j += 2) {
    BLOCK256(0, j)
    BLOCK256(1, j + 1)
  }

  // epilogue: C/D layout col = lane&15, row = (lane>>4)*4 + reg
  const int lr = lane >> 4, lc = lane & 15;
#pragma unroll
  for (int rb = 0; rb < 8; ++rb) {
#pragma unroll
    for (int r = 0; r < 4; ++r) {
      const int row = m0 + wm * 128 + rb * 16 + lr * 4 + r;
      float bM = 0.f;
      if (BIAS == 1) bM = bias[row];
      const long long ro = (long long)row * ldc;
#pragma unroll
      for (int cb = 0; cb < 4; ++cb) {
        const int col = n0 + wn * 64 + cb * 16 + lc;
        float v = acc[rb][cb][r] * scale;
        if (BIAS == 1) v += bM;
        if (BIAS == 2) v += bias[col];
        if constexpr (sizeof(OutT) == 2)
          C[ro + col] = f2h(v);
        else
          C[ro + col] = v;
      }
    }
  }
}

// fp32 -> fp16 elementwise cast, 4 elems/thread
__global__ void cast_f16(const float* __restrict__ in, short* __restrict__ out,
                         long long n) {
  long long i = ((long long)blockIdx.x * blockDim.x + threadIdx.x) * 4;
  if (i + 3 < n) {
    float4 v = *(const float4*)(in + i);
    halfx4s o;
    o[0] = f2h(v.x);
    o[1] = f2h(v.y);
    o[2] = f2h(v.z);
    o[3] = f2h(v.w);
    *(halfx4s*)(out + i) = o;
  }
}

// x[b][c][p] fp32 -> xT[b][p][c] fp16   (dim x dim per batch)
__global__ void transpose_cast(const float* __restrict__ x, short* __restrict__ xT,
                               int dim) {
  __shared__ float tile[64][65];
  const long long b = blockIdx.z;
  const float* xb = x + b * dim * (long long)dim;
  short* xTb = xT + b * dim * (long long)dim;
  const int c0 = blockIdx.y * 64, p0 = blockIdx.x * 64;
  const int tx = threadIdx.x & 63, ty = threadIdx.x >> 6;
#pragma unroll
  for (int i = 0; i < 64; i += 4)
    tile[ty + i][tx] = xb[(long long)(c0 + ty + i) * dim + p0 + tx];
  __syncthreads();
#pragma unroll
  for (int i = 0; i < 64; i += 4)
    xTb[(long long)(p0 + ty + i) * dim + c0 + tx] = f2h(tile[tx][ty + i]);
}

// row-wise softmax over 512 fp32 -> fp16; one 256-thread block per row
__global__ void softmax_rows(const float* __restrict__ S, short* __restrict__ P) {
  const long long row = blockIdx.x;
  const float* s = S + row * 512;
  const int t = threadIdx.x;
  float v0 = s[t], v1 = s[t + 256];
  float m = fmaxf(v0, v1);
  for (int o = 32; o; o >>= 1) m = fmaxf(m, __shfl_xor(m, o));
  __shared__ float red[4];
  const int wave = t >> 6, lane = t & 63;
  if (lane == 0) red[wave] = m;
  __syncthreads();
  m = fmaxf(fmaxf(red[0], red[1]), fmaxf(red[2], red[3]));
  float e0 = expf(v0 - m), e1 = expf(v1 - m);
  float sum = e0 + e1;
  for (int o = 32; o; o >>= 1) sum += __shfl_xor(sum, o);
  __syncthreads();
  if (lane == 0) red[wave] = sum;
  __syncthreads();
  sum = red[0] + red[1] + red[2] + red[3];
  const float inv = 1.0f / sum;
  short* p = P + row * 512;
  p[t] = f2h(e0 * inv);
  p[t + 256] = f2h(e1 * inv);
}

extern "C" void kernel_launch(void* const* d_in, const int* in_sizes, int n_in,
                              void* d_out, int out_size, void* d_ws, size_t ws_size,
                              hipStream_t stream) {
  const float* x    = (const float*)d_in[0];
  const float* Wqkv = (const float*)d_in[1];
  const float* bqkv = (const float*)d_in[2];
  const float* Wq   = (const float*)d_in[3];
  const float* bq   = (const float*)d_in[4];
  const float* Wk   = (const float*)d_in[5];
  const float* bk   = (const float*)d_in[6];
  const float* Wv   = (const float*)d_in[7];
  const float* bv   = (const float*)d_in[8];
  const float* Wout = (const float*)d_in[9];
  const float* bout = (const float*)d_in[10];
  float* out = (float*)d_out;

  const long long C = 4096, CPH = 512, P = 4096;

  size_t off = 0;
  auto alloc = [&](size_t bytes) -> char* {
    char* p = (char*)d_ws + off;
    off += (bytes + 255) & ~(size_t)255;
    return p;
  };
  short* Wqkv_b = (short*)alloc(3 * C * C * 2);   // reused as k2 after G1
  short* Wq_b   = (short*)alloc(C * C * 2);
  short* Wk_b   = (short*)alloc(C * C * 2);
  short* Wv_b   = (short*)alloc(C * C * 2);
  short* Wout_b = (short*)alloc(C * C * 2);
  short* xT     = (short*)alloc(2 * C * P * 2);   // reused as q2 after G1
  short* qkv    = (short*)alloc(2 * 3 * C * P * 2);
  short* v2T    = (short*)alloc(16 * C * CPH * 2);
  float* S      = (float*)alloc(16 * CPH * CPH * 4);
  short* Pm     = (short*)alloc(16 * CPH * CPH * 2);
  short* outT   = (short*)alloc(2 * C * P * 2);
  short* q2 = xT;
  short* k2 = Wqkv_b;
  if (off > ws_size) return;  // workspace too small: bail (will fail check loudly)

  // --- casts + transpose ---
  cast_f16<<<dim3((unsigned)(3 * C * C / 4 / 256)), 256, 0, stream>>>(Wqkv, Wqkv_b, 3 * C * C);
  cast_f16<<<dim3((unsigned)(C * C / 4 / 256)), 256, 0, stream>>>(Wq, Wq_b, C * C);
  cast_f16<<<dim3((unsigned)(C * C / 4 / 256)), 256, 0, stream>>>(Wk, Wk_b, C * C);
  cast_f16<<<dim3((unsigned)(C * C / 4 / 256)), 256, 0, stream>>>(Wv, Wv_b, C * C);
  cast_f16<<<dim3((unsigned)(C * C / 4 / 256)), 256, 0, stream>>>(Wout, Wout_b, C * C);
  transpose_cast<<<dim3(64, 64, 2), 256, 0, stream>>>(x, xT, 4096);

  // --- G1: qkv[b][o][p] = Wqkv . xT^T + bqkv  (M=12288,N=4096,K=4096, z=b) ---
  gemm256_nt<short, 1><<<dim3(16, 48, 2), 512, 0, stream>>>(
      Wqkv_b, xT, qkv, bqkv, 4096, 4096, 4096, 4096, 1.f,
      0, 0, C * P, 0, 3 * C * P, 0, 1);

  // --- G2: q2[b][hc][m] = qkv_q . Wq^T + bq(col) ---
  gemm256_nt<short, 2><<<dim3(16, 16, 2), 512, 0, stream>>>(
      qkv, Wq_b, q2, bq, 4096, 4096, 4096, 4096, 1.f,
      3 * C * P, 0, 0, 0, C * P, 0, 1);

  // --- G3: k2 = qkv_k . Wk^T + bk(col) ---
  gemm256_nt<short, 2><<<dim3(16, 16, 2), 512, 0, stream>>>(
      qkv + C * P, Wk_b, k2, bk, 4096, 4096, 4096, 4096, 1.f,
      3 * C * P, 0, 0, 0, C * P, 0, 1);

  // --- G4: v2T[z][m][d] = Wv . v_slice^T + bv(row)  (M=4096,N=512,K=4096, z=b*8+h) ---
  gemm256_nt<short, 1><<<dim3(2, 16, 16), 512, 0, stream>>>(
      Wv_b, qkv + 2 * C * P, v2T, bv, 4096, 4096, 4096, 512, 1.f,
      0, 0, 3 * C * P, CPH * P, 8 * C * CPH, C * CPH, 8);

  // --- G5: S[z][c][d] = 0.125 * q2_slice . k2_slice^T  (M=512,N=512,K=4096) ---
  gemm_nt<float, 0><<<dim3(4, 4, 16), 256, 0, stream>>>(
      q2, k2, S, nullptr, 4096, 4096, 4096, 512, 0.125f,
      C * P, CPH * P, C * P, CPH * P, 8 * CPH * CPH, CPH * CPH, 8);

  // --- softmax rows (16*512 rows of 512) ---
  softmax_rows<<<dim3(16 * 512), 256, 0, stream>>>(S, Pm);

  // --- G6: outT[b][m][h*512+c] = v2T_slice . P_slice^T  (M=4096,N=512,K=512) ---
  gemm_nt<short, 0><<<dim3(4, 32, 16), 256, 0, stream>>>(
      v2T, Pm, outT, nullptr, 512, 512, 512, 4096, 1.f,
      8 * C * CPH, C * CPH, 8 * CPH * CPH, CPH * CPH, C * P, 512, 8);

  // --- G7: out[b][o][p] = Wout . outT^T + bout(row)  (M=N=K=4096, fp32 out) ---
  gemm256_nt<float, 1><<<dim3(16, 16, 2), 512, 0, stream>>>(
      Wout_b, outT, out, bout, 4096, 4096, 4096, 4096, 1.f,
      0, 0, C * P, 0, C * P, 0, 1);
}